// Round 1
// baseline (1868.195 us; speedup 1.0000x reference)
//
#include <hip/hip_runtime.h>

// GR4J daily hydrological model, fused single kernel.
// T=4015 total steps, WARMUP=365 (output only for t>=365), B=2048 basins.
// One thread per basin: the two scans (production store s, routing store r)
// are sequential nonlinear recurrences in t; basins are independent.
// block=64 (one wave), grid=32 -> spreads the 32 waves across 32 CUs.

#define T_TOTAL 4015
#define NWARM   365
#define NB      2048

__global__ __launch_bounds__(64, 1)
void gr4j_kernel(const float2* __restrict__ pe_in,   // [T_TOTAL * NB] as (p,e) pairs
                 const float*  __restrict__ params,  // [NB, 4]
                 float*        __restrict__ out)     // [(T_TOTAL-NWARM) * NB]
{
    const int b = blockIdx.x * 64 + threadIdx.x;
    if (b >= NB) return;

    // Parameter affine transforms (X1S/X2S/X3S/X4S ranges)
    const float x1 = 100.0f + params[b * 4 + 0] * 1100.0f;   // [100, 1200)
    const float x2 = -5.0f  + params[b * 4 + 1] * 8.0f;      // [-5, 3)
    const float x3 = 20.0f  + params[b * 4 + 2] * 280.0f;    // [20, 300)
    const float x4 = 1.1f   + params[b * 4 + 3] * 1.8f;      // [1.1, 2.9)
    const float invx1 = 1.0f / x1;
    const float invx3 = 1.0f / x3;

    // --- Unit-hydrograph ordinates (once per thread; powf is fine here) ---
    float uh1k[3], uh2k[6];
    {
        float prev = 0.0f;
        #pragma unroll
        for (int j = 1; j <= 3; ++j) {
            float rr = fminf((float)j / x4, 1.0f);
            float sh = powf(rr, 2.5f);            // SH1(j) = min(j/x4,1)^2.5
            uh1k[j - 1] = sh - prev;
            prev = sh;
        }
        prev = 0.0f;
        #pragma unroll
        for (int j = 1; j <= 6; ++j) {
            float rr = (float)j / x4;
            float sh;
            if ((float)j <= x4) sh = 0.5f * powf(rr, 2.5f);
            else                sh = 1.0f - 0.5f * powf(fmaxf(2.0f - rr, 0.0f), 2.5f);
            uh2k[j - 1] = sh - prev;
            prev = sh;
        }
    }

    float s = 0.5f * x1;   // production store
    float r = 0.5f * x3;   // routing store
    // PR history pr[t-1..t-5] for the 3-tap (UH1) and 6-tap (UH2) causal convs
    float ph0 = 0.0f, ph1 = 0.0f, ph2 = 0.0f, ph3 = 0.0f, ph4 = 0.0f;

    // One GR4J timestep. All branches on t are wave-uniform.
    auto step = [&](int t, float2 pe) {
        const float diff = pe.x - pe.y;
        const float pn = fmaxf(diff, 0.0f);
        const float en = fmaxf(-diff, 0.0f);

        // tanh(x) for x = pn/x1, en/x1 <= 1/100: x*(1 - x^2/3) is exact to
        // < 2e-9 relative (next series term 2x^4/15 <= 1.3e-9) — no libm.
        const float ap = pn * invx1;
        const float ae = en * invx1;
        const float tp = ap * (1.0f - (1.0f / 3.0f) * ap * ap);
        const float te = ae * (1.0f - (1.0f / 3.0f) * ae * ae);

        // --- production store ---
        s = fminf(fmaxf(s, 0.0f), x1);
        const float sx = s * invx1;
        const float ps = x1 * (1.0f - sx * sx) * tp / (1.0f + sx * tp);
        const float es = s * (2.0f - sx) * te / (1.0f + (1.0f - sx) * te);
        float s2 = fminf(fmaxf(s - es + ps, 0.0f), x1);
        // perc: s_new = s2*(1+u^4)^(-1/4); perc = s2 - s_new (algebraically
        // identical to the reference's perc formula)
        const float u  = (4.0f / 9.0f) * s2 * invx1;
        const float u2 = u * u;
        const float u4 = u2 * u2;
        const float q4 = sqrtf(sqrtf(1.0f + u4));
        const float s_new = s2 / q4;
        const float pr = (s2 - s_new) + (pn - ps);
        s = s_new;

        // Conv history resets at the warmup boundary: the reference runs
        // _gr4j_core separately on p_and_e[WARMUP:], so UH convs restart with
        // zero-padded history while s and r carry over.
        if (t == NWARM) { ph0 = ph1 = ph2 = ph3 = ph4 = 0.0f; }

        const float q9 = uh1k[0] * pr + uh1k[1] * ph0 + uh1k[2] * ph1;
        const float q1 = uh2k[0] * pr + uh2k[1] * ph0 + uh2k[2] * ph1
                       + uh2k[3] * ph2 + uh2k[4] * ph3 + uh2k[5] * ph4;
        ph4 = ph3; ph3 = ph2; ph2 = ph1; ph1 = ph0; ph0 = pr;

        // --- routing store ---
        r = fminf(fmaxf(r, 0.0f), x3);
        const float rx = r * invx3;
        const float gex = x2 * (rx * rx * rx) * sqrtf(rx);   // x2*(r/x3)^3.5
        const float r2 = fmaxf(0.0f, r + q9 + gex);
        const float v  = r2 * invx3;
        const float v2 = v * v;
        const float v4 = v2 * v2;
        const float w4 = sqrtf(sqrtf(1.0f + v4));
        const float r_new = r2 / w4;   // r2*(1+v^4)^(-1/4)
        const float qr = r2 - r_new;
        const float qd = fmaxf(0.0f, q1 + gex);
        r = r_new;

        if (t >= NWARM) out[(size_t)(t - NWARM) * NB + b] = qr + qd;
    };

    // 8-deep register prefetch pipeline: loads (coalesced float2/lane) are
    // independent of the state chain; keep ~8 iterations (~1-2k cycles) of
    // latency cover so HBM misses never stall the recurrence.
    constexpr int PF = 8;
    float2 buf[PF];
    #pragma unroll
    for (int i = 0; i < PF; ++i) buf[i] = pe_in[(size_t)i * NB + b];

    const int TMAIN = (T_TOTAL / PF) * PF;   // 4008
    for (int t0 = 0; t0 < TMAIN; t0 += PF) {
        #pragma unroll
        for (int i = 0; i < PF; ++i) {
            const int t = t0 + i;
            const float2 pe = buf[i];
            const int tn = t + PF;
            buf[i] = (tn < T_TOTAL) ? pe_in[(size_t)tn * NB + b]
                                    : make_float2(0.0f, 0.0f);
            step(t, pe);
        }
    }
    #pragma unroll
    for (int t = TMAIN; t < T_TOTAL; ++t) {
        step(t, buf[t - TMAIN]);
    }
}

extern "C" void kernel_launch(void* const* d_in, const int* in_sizes, int n_in,
                              void* d_out, int out_size, void* d_ws, size_t ws_size,
                              hipStream_t stream) {
    const float2* pe_in  = (const float2*)d_in[0];   // p_and_e [4015,2048,2]
    const float*  params = (const float*)d_in[1];    // parameters [2048,4]
    float* out = (float*)d_out;                      // [3650,2048,1]
    (void)in_sizes; (void)n_in; (void)out_size; (void)d_ws; (void)ws_size;

    gr4j_kernel<<<dim3(NB / 64), dim3(64), 0, stream>>>(pe_in, params, out);
}

// Round 2
// 804.147 us; speedup vs baseline: 2.3232x; 2.3232x over previous
//
#include <hip/hip_runtime.h>

// GR4J daily hydrological model, fused single kernel, round 2.
// T=4015 total steps, WARMUP=365 (output only for t>=365), B=2048 basins.
// One thread per basin: the two scans (production store s, routing store r)
// are sequential nonlinear recurrences in t; basins are independent.
//
// R2 changes vs R1 (R1: 1798 us, ~1075 cyc/step, issue-bound on precise
// div/sqrt expansions):
//  - v_rcp_f32 / v_rsq_f32 / v_sqrt_f32 via __builtin_amdgcn_* (~1 ulp each)
//    instead of precise div/sqrt sequences.
//  - software pipeline: routing(t-1) emitted adjacent to production(t); the
//    two dependency chains (r-chain, s-chain) overlap instead of serializing.

#define T_TOTAL 4015
#define NWARM   365
#define NB      2048

__global__ __launch_bounds__(64, 1)
void gr4j_kernel(const float2* __restrict__ pe_in,   // [T_TOTAL * NB] as (p,e)
                 const float*  __restrict__ params,  // [NB, 4]
                 float*        __restrict__ out)     // [(T_TOTAL-NWARM) * NB]
{
    const int b = blockIdx.x * 64 + threadIdx.x;
    if (b >= NB) return;

    const float x1 = 100.0f + params[b * 4 + 0] * 1100.0f;   // [100, 1200)
    const float x2 = -5.0f  + params[b * 4 + 1] * 8.0f;      // [-5, 3)
    const float x3 = 20.0f  + params[b * 4 + 2] * 280.0f;    // [20, 300)
    const float x4 = 1.1f   + params[b * 4 + 3] * 1.8f;      // [1.1, 2.9)
    const float invx1 = __builtin_amdgcn_rcpf(x1);
    const float invx3 = __builtin_amdgcn_rcpf(x3);

    // --- Unit-hydrograph ordinates (once per thread; precise powf is fine) ---
    float uh1k[3], uh2k[6];
    {
        float prev = 0.0f;
        #pragma unroll
        for (int j = 1; j <= 3; ++j) {
            float rr = fminf((float)j / x4, 1.0f);
            float sh = powf(rr, 2.5f);            // SH1(j) = min(j/x4,1)^2.5
            uh1k[j - 1] = sh - prev;
            prev = sh;
        }
        prev = 0.0f;
        #pragma unroll
        for (int j = 1; j <= 6; ++j) {
            float rr = (float)j / x4;
            float sh;
            if ((float)j <= x4) sh = 0.5f * powf(rr, 2.5f);
            else                sh = 1.0f - 0.5f * powf(fmaxf(2.0f - rr, 0.0f), 2.5f);
            uh2k[j - 1] = sh - prev;
            prev = sh;
        }
    }

    float s = 0.5f * x1;   // production store
    float r = 0.5f * x3;   // routing store
    // PR history pr[t-1..t-5] for the 3-tap (UH1) and 6-tap (UH2) convs
    float ph0 = 0.0f, ph1 = 0.0f, ph2 = 0.0f, ph3 = 0.0f, ph4 = 0.0f;
    // pipeline registers: (q9,q1) produced at step t, consumed by routing at
    // the next loop iteration
    float q9p = 0.0f, q1p = 0.0f;

    // Production half-step for time t: consumes s, updates s/ph*, emits q9/q1.
    auto prod = [&](int t, float2 pe, float& q9o, float& q1o) {
        const float diff = pe.x - pe.y;
        const float pn = fmaxf(diff, 0.0f);
        const float en = fmaxf(-diff, 0.0f);

        // tanh(x), x <= 1/100: x*(1 - x^2/3), error < 2e-9 relative.
        const float ap = pn * invx1;
        const float ae = en * invx1;
        const float tp = ap * (1.0f - (1.0f / 3.0f) * ap * ap);
        const float te = ae * (1.0f - (1.0f / 3.0f) * ae * ae);

        s = fminf(fmaxf(s, 0.0f), x1);
        const float sx = s * invx1;
        const float ps = x1 * (1.0f - sx * sx) * tp
                         * __builtin_amdgcn_rcpf(1.0f + sx * tp);
        const float es = s * (2.0f - sx) * te
                         * __builtin_amdgcn_rcpf(1.0f + (1.0f - sx) * te);
        float s2 = fminf(fmaxf(s - es + ps, 0.0f), x1);
        // s_new = s2*(1+u^4)^(-1/4) = s2 * rsq(sqrt(1+u^4)); perc = s2 - s_new
        const float u  = (4.0f / 9.0f) * s2 * invx1;
        const float u2 = u * u;
        const float u4 = u2 * u2;
        const float s_new = s2 * __builtin_amdgcn_rsqf(__builtin_amdgcn_sqrtf(1.0f + u4));
        const float pr = (s2 - s_new) + (pn - ps);
        s = s_new;

        // Conv history resets at the warmup boundary (reference runs
        // _gr4j_core fresh on p_and_e[WARMUP:]; s,r carry over, convs don't).
        if (t == NWARM) { ph0 = ph1 = ph2 = ph3 = ph4 = 0.0f; }

        // History partial sums only depend on ph* (available early) — off the
        // pr critical path; only the final fma with pr is on-chain.
        const float q9h = fmaf(uh1k[1], ph0, uh1k[2] * ph1);
        const float q1h = fmaf(uh2k[1], ph0,
                          fmaf(uh2k[2], ph1,
                          fmaf(uh2k[3], ph2,
                          fmaf(uh2k[4], ph3, uh2k[5] * ph4))));
        q9o = fmaf(uh1k[0], pr, q9h);
        q1o = fmaf(uh2k[0], pr, q1h);
        ph4 = ph3; ph3 = ph2; ph2 = ph1; ph1 = ph0; ph0 = pr;
    };

    // Routing half-step for time tr: consumes r and (q9,q1) of step tr.
    auto route = [&](int tr, float q9, float q1) {
        r = fminf(fmaxf(r, 0.0f), x3);
        const float rx = r * invx3;
        const float gex = x2 * (rx * rx * rx) * __builtin_amdgcn_sqrtf(rx); // x2*rx^3.5
        const float r2 = fmaxf(0.0f, r + q9 + gex);
        const float v  = r2 * invx3;
        const float v2 = v * v;
        const float v4 = v2 * v2;
        const float r_new = r2 * __builtin_amdgcn_rsqf(__builtin_amdgcn_sqrtf(1.0f + v4));
        const float qr = r2 - r_new;
        const float qd = fmaxf(0.0f, q1 + gex);
        r = r_new;
        if (tr >= NWARM) out[(size_t)(tr - NWARM) * NB + b] = qr + qd;
    };

    // 8-deep register prefetch pipeline for the coalesced float2 input stream.
    constexpr int PF = 8;
    float2 buf[PF];
    #pragma unroll
    for (int i = 0; i < PF; ++i) buf[i] = pe_in[(size_t)i * NB + b];

    const int TMAIN = (T_TOTAL / PF) * PF;   // 4008
    for (int t0 = 0; t0 < TMAIN; t0 += PF) {
        #pragma unroll
        for (int i = 0; i < PF; ++i) {
            const int t = t0 + i;
            const float2 pe = buf[i];
            const int tn = t + PF;
            buf[i] = (tn < T_TOTAL) ? pe_in[(size_t)tn * NB + b]
                                    : make_float2(0.0f, 0.0f);
            // routing for t-1 and production for t are independent chains;
            // adjacent straight-line code lets the scheduler interleave them.
            float q9n, q1n;
            prod(t, pe, q9n, q1n);
            if (t > 0) route(t - 1, q9p, q1p);
            q9p = q9n; q1p = q1n;
        }
    }
    #pragma unroll
    for (int t = TMAIN; t < T_TOTAL; ++t) {
        float q9n, q1n;
        prod(t, buf[t - TMAIN], q9n, q1n);
        route(t - 1, q9p, q1p);
        q9p = q9n; q1p = q1n;
    }
    route(T_TOTAL - 1, q9p, q1p);
}

extern "C" void kernel_launch(void* const* d_in, const int* in_sizes, int n_in,
                              void* d_out, int out_size, void* d_ws, size_t ws_size,
                              hipStream_t stream) {
    const float2* pe_in  = (const float2*)d_in[0];   // p_and_e [4015,2048,2]
    const float*  params = (const float*)d_in[1];    // parameters [2048,4]
    float* out = (float*)d_out;                      // [3650,2048,1]
    (void)in_sizes; (void)n_in; (void)out_size; (void)d_ws; (void)ws_size;

    gr4j_kernel<<<dim3(NB / 64), dim3(64), 0, stream>>>(pe_in, params, out);
}

// Round 3
// 605.325 us; speedup vs baseline: 3.0863x; 1.3285x over previous
//
#include <hip/hip_runtime.h>

// GR4J daily hydrological model, fused single kernel, round 3.
// T=4015 steps, WARMUP=365 (store only t>=365), B=2048 basins, 1 thread/basin.
//
// R3 vs R2 (R2: 750 us ~ 448 cyc/step, issue-bound: ~160 VALU insts/step vs
// ~55 of math — per-step uniform branches + bounds selects + 64-bit address
// recompute):
//  - phase-split loops: warmup (no store) / main (always store); conv-history
//    reset once between phases; no per-step conditionals of any kind.
//  - explicit 10-deep prefetch pipeline with refill/drain tails so every load
//    is unconditional and in-bounds by construction.
//  - pointer-bump addressing (per-block base + constant unrolled offsets).
//  - chain surgery: dropped provably-no-op clamps (s_new in [0,x1] and
//    r_new in [0,x3) are loop invariants with margin >> ulp); ps/es share one
//    rcp(dp*de); u^4 = c4s*s2^4 with precomputed c4s; fma(u2,u2,1).

#define T_TOTAL 4015
#define NWARM   365
#define NB      2048
#define PF      10

__global__ __launch_bounds__(64, 1)
void gr4j_kernel(const float2* __restrict__ pe_in,   // [T_TOTAL*NB] (p,e)
                 const float*  __restrict__ params,  // [NB,4]
                 float*        __restrict__ out)     // [(T_TOTAL-NWARM)*NB]
{
    const int b = blockIdx.x * 64 + threadIdx.x;     // grid covers exactly NB

    const float x1 = 100.0f + params[b * 4 + 0] * 1100.0f;
    const float x2 = -5.0f  + params[b * 4 + 1] * 8.0f;
    const float x3 = 20.0f  + params[b * 4 + 2] * 280.0f;
    const float x4 = 1.1f   + params[b * 4 + 3] * 1.8f;
    const float invx1 = __builtin_amdgcn_rcpf(x1);
    const float invx3 = __builtin_amdgcn_rcpf(x3);
    const float c49   = (4.0f / 9.0f) * invx1;
    const float c49_2 = c49 * c49;
    const float c4s   = c49_2 * c49_2;          // ((4/9)/x1)^4
    const float i3_2  = invx3 * invx3;
    const float c4r   = i3_2 * i3_2;            // (1/x3)^4

    // Unit-hydrograph ordinates (once; precise powf fine here).
    float u10, u11, u12, u20, u21, u22, u23, u24, u25;
    {
        float sh[7];
        #pragma unroll
        for (int j = 1; j <= 3; ++j)
            sh[j] = powf(fminf((float)j / x4, 1.0f), 2.5f);
        u10 = sh[1]; u11 = sh[2] - sh[1]; u12 = sh[3] - sh[2];
        float s2h[7]; s2h[0] = 0.0f;
        #pragma unroll
        for (int j = 1; j <= 6; ++j) {
            float rr = (float)j / x4;
            s2h[j] = ((float)j <= x4) ? 0.5f * powf(rr, 2.5f)
                   : 1.0f - 0.5f * powf(fmaxf(2.0f - rr, 0.0f), 2.5f);
        }
        u20 = s2h[1];          u21 = s2h[2] - s2h[1]; u22 = s2h[3] - s2h[2];
        u23 = s2h[4] - s2h[3]; u24 = s2h[5] - s2h[4]; u25 = s2h[6] - s2h[5];
    }

    float s = 0.5f * x1;                 // production store (invariant: [0,x1])
    float r = 0.5f * x3;                 // routing store   (invariant: [0,x3))
    float ph0 = 0.f, ph1 = 0.f, ph2 = 0.f, ph3 = 0.f, ph4 = 0.f;
    float q9p = 0.f, q1p = 0.f;          // prod(t) -> route(t) pipeline regs

    // Production step: consumes s + pe, updates s/ph*/q9p/q1p. No branches.
    auto prod = [&](float2 pe) {
        const float diff = pe.x - pe.y;
        const float pn = fmaxf(diff, 0.0f);
        const float en = fmaxf(-diff, 0.0f);
        // tanh(x), x<=0.01: x - x^3/3 (rel err < 2e-9)
        const float ap = pn * invx1;
        const float ae = en * invx1;
        const float tp = fmaf(ap * (ap * ap), -(1.0f / 3.0f), ap);
        const float te = fmaf(ae * (ae * ae), -(1.0f / 3.0f), ae);

        const float sx = s * invx1;
        const float dp = fmaf(sx, tp, 1.0f);             // 1 + sx*tp
        const float de = fmaf(1.0f - sx, te, 1.0f);      // 1 + (1-sx)*te
        const float nump = x1 * tp * fmaf(-sx, sx, 1.0f);    // x1(1-sx^2)tp
        const float nume = s * te * (2.0f - sx);             // s(2-sx)te
        const float rpe = __builtin_amdgcn_rcpf(dp * de);
        const float a_ = nump * de;                      // ps*(dp*de)
        const float b_ = nume * dp;                      // es*(dp*de)
        const float s2 = fmaf(a_ - b_, rpe, s);          // s - es + ps
        const float ps = a_ * rpe;                       // off the s-chain
        // perc: s_new = s2*(1+u^4)^(-1/4), u^4 = c4s*s2^4
        const float s22 = s2 * s2;
        const float s24 = s22 * s22;
        const float u4p1 = fmaf(c4s, s24, 1.0f);
        const float s_new = s2 * __builtin_amdgcn_rsqf(__builtin_amdgcn_sqrtf(u4p1));
        const float pr = (s2 - s_new) + (pn - ps);       // perc + (pn - ps)
        s = s_new;

        const float q9h = fmaf(u11, ph0, u12 * ph1);
        const float q1h = fmaf(u21, ph0, fmaf(u22, ph1,
                          fmaf(u23, ph2, fmaf(u24, ph3, u25 * ph4))));
        q9p = fmaf(u10, pr, q9h);
        q1p = fmaf(u20, pr, q1h);
        ph4 = ph3; ph3 = ph2; ph2 = ph1; ph1 = ph0; ph0 = pr;
    };

    // Routing step: consumes r + (q9p,q1p), updates r, returns q. No branches.
    auto route_q = [&]() -> float {
        const float rx = r * invx3;
        const float srx = __builtin_amdgcn_sqrtf(rx);
        const float rx3 = (rx * rx) * rx;
        const float gex = x2 * rx3 * srx;                // x2*(r/x3)^3.5
        const float r2 = fmaxf(0.0f, (r + q9p) + gex);
        const float r22 = r2 * r2;
        const float r24 = r22 * r22;
        const float v4p1 = fmaf(c4r, r24, 1.0f);
        const float r_new = r2 * __builtin_amdgcn_rsqf(__builtin_amdgcn_sqrtf(v4p1));
        const float qr = r2 - r_new;
        const float qd = fmaxf(0.0f, q1p + gex);
        r = r_new;
        return qr + qd;
    };

    const float2* ip = pe_in + b;        // lane base (row stride NB float2)
    float2 buf[PF];
    #pragma unroll
    for (int i = 0; i < PF; ++i) buf[i] = ip[i * NB];

    // ================= Phase A: t = 0..364, no stores =================
    prod(buf[0]);                        // t=0
    buf[0] = ip[PF * NB];                // refill slot 0 with pe[10]
    {
        const float2* p2 = ip + NB;      // block base: t=1
        for (int j = 0; j < 36; ++j) {   // t = 1+10j .. 10+10j  (1..360)
            #pragma unroll
            for (int i = 0; i < PF; ++i) {
                const int slot = (i + 1) % PF;       // compile-time
                const float2 pe = buf[slot];
                buf[slot] = p2[(i + PF) * NB];       // pe[t+10] <= pe[370]
                (void)route_q();                     // route(t-1), no store
                prod(pe);                            // prod(t)
            }
            p2 += PF * NB;
        }
        // drain tail: t = 361..364 from slots 1..4
        #pragma unroll
        for (int i = 0; i < 4; ++i) {
            (void)route_q();             // route(360+i)
            prod(buf[i + 1]);            // prod(361+i)
        }
        (void)route_q();                 // route(364)
    }

    // ========== Phase B: t = 365..4014, store every step ==========
    // Reference runs _gr4j_core fresh on p_and_e[WARMUP:]: conv history
    // resets to zero; s and r carry over.
    ph0 = ph1 = ph2 = ph3 = ph4 = 0.0f;

    const float2* q2 = pe_in + (size_t)NWARM * NB + b;
    #pragma unroll
    for (int i = 0; i < PF; ++i) buf[i] = q2[i * NB];   // pe[365..374]

    prod(buf[0]);                        // t=365
    buf[0] = q2[PF * NB];                // refill: pe[375]
    {
        const float2* pB = q2 + NB;      // block base: t=366
        float* opB = out + b;            // out row 0 = t=365's route
        for (int j = 0; j < 363; ++j) {  // t = 366+10j .. 375+10j (366..3995)
            #pragma unroll
            for (int i = 0; i < PF; ++i) {
                const int slot = (i + 1) % PF;
                const float2 pe = buf[slot];
                buf[slot] = pB[(i + PF) * NB];       // pe[t+10] <= pe[4005]
                opB[i * NB] = route_q();             // route(t-1) -> row 10j+i
                prod(pe);                            // prod(t)
            }
            pB += PF * NB;
            opB += PF * NB;
        }
        // refill tail: t = 3996..4004 (9 steps), refills pe[4006..4014]
        #pragma unroll
        for (int i = 0; i < 9; ++i) {
            const int slot = (i + 1) % PF;
            const float2 pe = buf[slot];
            buf[slot] = pB[(i + PF) * NB];
            opB[i * NB] = route_q();                 // rows 3630..3638
            prod(pe);
        }
        opB += 9 * NB;                               // row 3639
        // drain tail: t = 4005..4014 (10 steps), slots 0..9, no refill
        #pragma unroll
        for (int i = 0; i < PF; ++i) {
            opB[i * NB] = route_q();                 // rows 3639..3648
            prod(buf[i]);                            // prod(4005+i)
        }
        opB[PF * NB] = route_q();                    // route(4014) -> row 3649
    }
}

extern "C" void kernel_launch(void* const* d_in, const int* in_sizes, int n_in,
                              void* d_out, int out_size, void* d_ws, size_t ws_size,
                              hipStream_t stream) {
    const float2* pe_in  = (const float2*)d_in[0];   // p_and_e [4015,2048,2]
    const float*  params = (const float*)d_in[1];    // parameters [2048,4]
    float* out = (float*)d_out;                      // [3650,2048,1]
    (void)in_sizes; (void)n_in; (void)out_size; (void)d_ws; (void)ws_size;

    gr4j_kernel<<<dim3(NB / 64), dim3(64), 0, stream>>>(pe_in, params, out);
}

// Round 5
// 404.269 us; speedup vs baseline: 4.6212x; 1.4973x over previous
//
#include <hip/hip_runtime.h>

// GR4J daily hydrological model, round 5: 2-wave producer/consumer pipeline.
// T=4015 steps, WARMUP=365, B=2048 basins.
//
// R4 -> R5: BUGFIX. R4's wave1 store bases used `lane` instead of the global
// basin index `b` (= blockIdx.x*64 + lane): all 32 blocks raced into basins
// 0..63 and basins 64..2047 were never written (absmax 1.98 ~= max|ref|,
// the "rows left at memset-0" signature). LDS indexing (lane, block-local)
// and load indexing (b) were correct. Fixed ob/dumpb/realb to use b.
//
// Design (unchanged from R4):
//   wave0: input load + net precip/evap + production store s-chain -> pr
//   wave1: 9-tap UH convolution + routing store r-chain + output store
// pr flows wave0 -> wave1 through double-buffered LDS in batches of 55 steps
// (73 batches x 55 = 4015; 55 = 5*11 keeps the 11-deep prefetch rotation's
// slot indices compile-time). One __syncthreads per batch iteration.
//
// Warmup without per-step predication: stores for t<365 go to out rows [t]
// (t<=364), later overwritten by the real rows (row j final-written at
// t=365+j; same-thread same-address stores are program-ordered). Batch kb=6
// (t=330..384) is fully unrolled: conv history resets before t=365 (the
// reference restarts _gr4j_core at WARMUP; s,r carry over, conv history
// does not) and the store base switches dump->real there.
//
// Approximations (budget: threshold 3.97e-2, R3 exact-form absmax 7.8e-3):
//  - tanh(x) ~= x for x<=0.01 (rel err <= 3.3e-5, self-limited feedback).
//  - (1+z)^(-1/4), z<=0.039: 3-term series (perc err <= 2.6e-4/step).
//  - routing keeps exact-form v_sqrt/v_rsq (its z is O(1)).

#define T_TOTAL 4015
#define NWARM   365
#define NB      2048
#define BSTEP   55
#define NBATCH  73          // 73 * 55 = 4015

__global__ __launch_bounds__(128, 1)
void gr4j_kernel(const float2* __restrict__ pe_in,   // [T_TOTAL*NB] (p,e)
                 const float*  __restrict__ params,  // [NB,4]
                 float*        __restrict__ out)     // [(T_TOTAL-NWARM)*NB]
{
    const int lane = threadIdx.x & 63;
    const int wid  = threadIdx.x >> 6;
    const int b    = blockIdx.x * 64 + lane;

    __shared__ float prbuf[2][BSTEP * 64];           // 28.2 KB

    const float x1 = 100.0f + params[b * 4 + 0] * 1100.0f;
    const float x2 = -5.0f  + params[b * 4 + 1] * 8.0f;
    const float x3 = 20.0f  + params[b * 4 + 2] * 280.0f;
    const float x4 = 1.1f   + params[b * 4 + 3] * 1.8f;
    const float invx1 = __builtin_amdgcn_rcpf(x1);
    const float invx3 = __builtin_amdgcn_rcpf(x3);
    const float c49   = (4.0f / 9.0f) * invx1;
    const float c49_2 = c49 * c49;
    const float c4s   = c49_2 * c49_2;               // ((4/9)/x1)^4
    const float i3_2  = invx3 * invx3;
    const float c4r   = i3_2 * i3_2;                 // (1/x3)^4

    // Unit-hydrograph ordinates (once; precise powf fine here).
    float u10, u11, u12, u20, u21, u22, u23, u24, u25;
    {
        float sh[3];
        #pragma unroll
        for (int j = 1; j <= 3; ++j)
            sh[j - 1] = powf(fminf((float)j / x4, 1.0f), 2.5f);
        u10 = sh[0]; u11 = sh[1] - sh[0]; u12 = sh[2] - sh[1];
        float s2h[6];
        #pragma unroll
        for (int j = 1; j <= 6; ++j) {
            float rr = (float)j / x4;
            s2h[j - 1] = ((float)j <= x4) ? 0.5f * powf(rr, 2.5f)
                       : 1.0f - 0.5f * powf(fmaxf(2.0f - rr, 0.0f), 2.5f);
        }
        u20 = s2h[0];          u21 = s2h[1] - s2h[0]; u22 = s2h[2] - s2h[1];
        u23 = s2h[3] - s2h[2]; u24 = s2h[4] - s2h[3]; u25 = s2h[5] - s2h[4];
    }

    float s = 0.5f * x1;                 // production store (wave0)
    float r = 0.5f * x3;                 // routing store (wave1)
    float ph0 = 0.f, ph1 = 0.f, ph2 = 0.f, ph3 = 0.f, ph4 = 0.f; // wave1

    // wave0: production step. Consumes s + pe, returns pr.
    auto prod_step = [&](float2 pe) -> float {
        const float diff = pe.x - pe.y;
        const float pn = fmaxf(diff, 0.0f);
        const float en = fmaxf(-diff, 0.0f);
        const float ap = pn * invx1;                 // ~= tanh(pn/x1)
        const float ae = en * invx1;                 // ~= tanh(en/x1)
        const float sx = s * invx1;
        const float dp = fmaf(sx, ap, 1.0f);
        const float de = fmaf(1.0f - sx, ae, 1.0f);
        const float n1 = fmaf(-sx, sx, 1.0f);
        const float nump = pn * n1;                  // x1*(1-sx^2)*(pn/x1)
        const float nume = (sx * en) * (2.0f - sx);  // s*(2-sx)*(en/x1)
        const float rpe = __builtin_amdgcn_rcpf(dp * de);
        const float a_ = nump * de;
        const float b_ = nume * dp;
        const float s2 = fmaf(a_ - b_, rpe, s);      // s - es + ps
        const float ps = a_ * rpe;
        const float s22 = s2 * s2;
        const float s24 = s22 * s22;
        const float z = c4s * s24;                   // ((4/9)s2/x1)^4 <= .039
        float w = fmaf(z, 15.0f / 128.0f, -5.0f / 32.0f);
        w = fmaf(z, w, 0.25f);
        const float perc = (s2 * z) * w;             // s2*(1-(1+z)^-.25)
        s = s2 - perc;
        return perc + (pn - ps);
    };

    // wave1: conv + routing step. Consumes r/ph* + pr, returns q.
    auto w1_step = [&](float pr) -> float {
        const float q9 = fmaf(u10, pr, fmaf(u11, ph0, u12 * ph1));
        const float q1 = fmaf(u20, pr, fmaf(u21, ph0, fmaf(u22, ph1,
                         fmaf(u23, ph2, fmaf(u24, ph3, u25 * ph4)))));
        ph4 = ph3; ph3 = ph2; ph2 = ph1; ph1 = ph0; ph0 = pr;
        const float rx = r * invx3;
        const float srx = __builtin_amdgcn_sqrtf(rx);
        const float gex = (x2 * ((rx * rx) * rx)) * srx;   // x2*(r/x3)^3.5
        const float r2 = fmaxf(0.0f, (r + q9) + gex);
        const float r22 = r2 * r2;
        const float r24 = r22 * r22;
        const float v4p1 = fmaf(c4r, r24, 1.0f);
        const float rn = r2 * __builtin_amdgcn_rsqf(__builtin_amdgcn_sqrtf(v4p1));
        const float qr = r2 - rn;
        r = rn;
        return qr + fmaxf(0.0f, q1 + gex);
    };

    // wave0's 11-deep global prefetch rotation (slot = t mod 11; batch size
    // 55 is a multiple of 11 so slots stay aligned at batch boundaries).
    const float2* gptr = pe_in + b;
    float2 rot[11];
    if (wid == 0) {
        #pragma unroll
        for (int i = 0; i < 11; ++i) rot[i] = gptr[(size_t)i * NB];
    }

    for (int k = 0; k <= NBATCH; ++k) {
        if (wid == 0) {
            if (k < NBATCH) {
                const int tb = k * BSTEP;
                float* dst = &prbuf[k & 1][0] + lane;
                const int grf = (k < NBATCH - 1) ? 5 : 4;  // groups w/ refill
                for (int g = 0; g < 5; ++g) {
                    float* d2 = dst + g * (11 * 64);
                    if (g < grf) {
                        const float2* gp = gptr + (size_t)(tb + g * 11 + 11) * NB;
                        #pragma unroll
                        for (int i = 0; i < 11; ++i) {
                            const float2 pe = rot[i];
                            rot[i] = gp[(size_t)i * NB];   // load t+11
                            d2[i * 64] = prod_step(pe);
                        }
                    } else {                               // final-batch drain
                        #pragma unroll
                        for (int i = 0; i < 11; ++i)
                            d2[i * 64] = prod_step(rot[i]);
                    }
                }
            }
        } else if (k >= 1) {
            const int kb = k - 1;
            const float* src = &prbuf[kb & 1][0] + lane;
            if (kb != 6) {
                // kb<6: t=kb*55..+54 <= 329 -> dump rows [t] (rewritten by
                // t'=365+row later). kb>=7: real rows [t-365].
                float* ob = (kb < 6)
                    ? out + (size_t)(kb * BSTEP) * NB + b
                    : out + (size_t)(kb * BSTEP - NWARM) * NB + b;
                float prr[11];
                #pragma unroll
                for (int i = 0; i < 11; ++i) prr[i] = src[i * 64];
                for (int g = 0; g < 5; ++g) {
                    const float* sp = src + (g + 1) * (11 * 64);
                    float* ob2 = ob + (size_t)(g * 11) * NB;
                    if (g < 4) {
                        #pragma unroll
                        for (int i = 0; i < 11; ++i) {
                            const float pr = prr[i];
                            prr[i] = sp[i * 64];           // prefetch 11 ahead
                            ob2[(size_t)i * NB] = w1_step(pr);
                        }
                    } else {
                        #pragma unroll
                        for (int i = 0; i < 11; ++i)
                            ob2[(size_t)i * NB] = w1_step(prr[i]);
                    }
                }
            } else {
                // Special batch kb=6: t=330..384. Conv-history reset before
                // t=365; store base switches dump->real at t=365. Fully
                // unrolled so every condition folds at compile time.
                float* dumpb = out + (size_t)330 * NB + b;     // rows 330..364
                float* realb = out + b;                        // rows 0..19
                float prr[11];
                #pragma unroll
                for (int i = 0; i < 11; ++i) prr[i] = src[i * 64];
                #pragma unroll
                for (int g = 0; g < 5; ++g) {
                    #pragma unroll
                    for (int i = 0; i < 11; ++i) {
                        const int j = g * 11 + i;              // step in batch
                        const float pr = prr[i];
                        if (g < 4) prr[i] = src[(j + 11) * 64];
                        if (j == 35) { ph0 = ph1 = ph2 = ph3 = ph4 = 0.0f; }
                        const float q = w1_step(pr);
                        if (j < 35) dumpb[(size_t)j * NB] = q;
                        else        realb[(size_t)(j - 35) * NB] = q;
                    }
                }
            }
        }
        __syncthreads();
    }
}

extern "C" void kernel_launch(void* const* d_in, const int* in_sizes, int n_in,
                              void* d_out, int out_size, void* d_ws, size_t ws_size,
                              hipStream_t stream) {
    const float2* pe_in  = (const float2*)d_in[0];   // p_and_e [4015,2048,2]
    const float*  params = (const float*)d_in[1];    // parameters [2048,4]
    float* out = (float*)d_out;                      // [3650,2048,1]
    (void)in_sizes; (void)n_in; (void)out_size; (void)d_ws; (void)ws_size;

    gr4j_kernel<<<dim3(NB / 64), dim3(128), 0, stream>>>(pe_in, params, out);
}

// Round 6
// 400.314 us; speedup vs baseline: 4.6668x; 1.0099x over previous
//
#include <hip/hip_runtime.h>

// GR4J daily hydrological model, round 6: decoupled 2-wave producer/consumer.
// T=4015 steps, WARMUP=365, B=2048 basins.
//
// R5 (404 us, ~203 cyc/step) sat 2.5x above both the issue floor (~64 cyc)
// and the r-chain latency floor (~76 cyc). Suspected structural cost: the
// per-batch __syncthreads forces s_waitcnt vmcnt(0) lgkmcnt(0) (compiler
// drains ALL in-flight global loads before s_barrier), and lockstep batches
// cost max(w0,w1)+drain each. R6 removes every barrier from the pipeline:
// LDS flag protocol (produced/consumed counters, __hip_atomic_* with
// workgroup scope, acquire/release -> ds ops + lgkmcnt only, no vmcnt
// drain). Waves drift; rates average; prefetch loads retire naturally.
//
//   wave0 (producer): input load (11-deep reg rotation) + production store
//     s-chain -> pr, written to double-buffered LDS (55 steps/batch).
//     Gated by consumed >= k-1 before overwriting buffer parity k&1.
//   wave1 (consumer): 9-tap UH conv + routing r-chain + output store.
//     Gated by produced >= k+1.
//
// Warmup without per-step predication: stores for t<365 go to out rows [t]
// (t<=364), later overwritten by the real rows (same wave, same address,
// program-ordered). Batch k=6 (t=330..384) fully unrolled: conv history
// reset before t=365 (reference restarts _gr4j_core at WARMUP; s,r carry
// over, conv history does not) + store base switches dump->real.
//
// Approximations (threshold 3.97e-2; measured absmax with these: 7.8e-3):
//  - tanh(x) ~= x for x<=0.01; (1+z)^(-1/4) 3-term series in prod (z<=.039);
//  - routing keeps exact-form v_sqrt/v_rsq.

#define T_TOTAL 4015
#define NWARM   365
#define NB      2048
#define BSTEP   55
#define NBATCH  73          // 73 * 55 = 4015

__global__ __launch_bounds__(128, 1)
void gr4j_kernel(const float2* __restrict__ pe_in,   // [T_TOTAL*NB] (p,e)
                 const float*  __restrict__ params,  // [NB,4]
                 float*        __restrict__ out)     // [(T_TOTAL-NWARM)*NB]
{
    const int lane = threadIdx.x & 63;
    const int wid  = threadIdx.x >> 6;
    const int b    = blockIdx.x * 64 + lane;

    __shared__ float prbuf[2][BSTEP * 64];           // 28.2 KB double buffer
    __shared__ int produced;                         // batches written by w0
    __shared__ int consumed;                         // batches read by w1
    if (threadIdx.x == 0) { produced = 0; consumed = 0; }
    __syncthreads();   // the only barrier: flag init (outside the pipeline)

    const float x1 = 100.0f + params[b * 4 + 0] * 1100.0f;
    const float x2 = -5.0f  + params[b * 4 + 1] * 8.0f;
    const float x3 = 20.0f  + params[b * 4 + 2] * 280.0f;
    const float x4 = 1.1f   + params[b * 4 + 3] * 1.8f;
    const float invx1 = __builtin_amdgcn_rcpf(x1);
    const float invx3 = __builtin_amdgcn_rcpf(x3);
    const float c49   = (4.0f / 9.0f) * invx1;
    const float c49_2 = c49 * c49;
    const float c4s   = c49_2 * c49_2;               // ((4/9)/x1)^4
    const float i3_2  = invx3 * invx3;
    const float c4r   = i3_2 * i3_2;                 // (1/x3)^4

    if (wid == 0) {
        // ================== producer: s-chain -> pr ==================
        float s = 0.5f * x1;

        auto prod_step = [&](float2 pe) -> float {
            const float diff = pe.x - pe.y;
            const float pn = fmaxf(diff, 0.0f);
            const float en = fmaxf(-diff, 0.0f);
            const float ap = pn * invx1;             // ~= tanh(pn/x1)
            const float ae = en * invx1;             // ~= tanh(en/x1)
            const float sx = s * invx1;
            const float dp = fmaf(sx, ap, 1.0f);
            const float de = fmaf(1.0f - sx, ae, 1.0f);
            const float n1 = fmaf(-sx, sx, 1.0f);
            const float nump = pn * n1;              // x1*(1-sx^2)*(pn/x1)
            const float nume = (sx * en) * (2.0f - sx);
            const float rpe = __builtin_amdgcn_rcpf(dp * de);
            const float a_ = nump * de;
            const float b_ = nume * dp;
            const float s2 = fmaf(a_ - b_, rpe, s);  // s - es + ps
            const float ps = a_ * rpe;
            const float s22 = s2 * s2;
            const float s24 = s22 * s22;
            const float z = c4s * s24;               // <= 0.039
            float w = fmaf(z, 15.0f / 128.0f, -5.0f / 32.0f);
            w = fmaf(z, w, 0.25f);
            const float perc = (s2 * z) * w;         // s2*(1-(1+z)^-.25)
            s = s2 - perc;
            return perc + (pn - ps);
        };

        const float2* gptr = pe_in + b;
        float2 rot[11];                              // 11-deep prefetch
        #pragma unroll
        for (int i = 0; i < 11; ++i) rot[i] = gptr[(size_t)i * NB];

        for (int k = 0; k < NBATCH; ++k) {
            if (k >= 2) {
                while (__hip_atomic_load(&consumed, __ATOMIC_ACQUIRE,
                                         __HIP_MEMORY_SCOPE_WORKGROUP) < k - 1) {}
            }
            float* dst = &prbuf[k & 1][0] + lane;
            const int tb = k * BSTEP;
            const int grf = (k < NBATCH - 1) ? 5 : 4;    // groups w/ refill
            for (int g = 0; g < 5; ++g) {
                float* d2 = dst + g * (11 * 64);
                if (g < grf) {
                    const float2* gp = gptr + (size_t)(tb + g * 11 + 11) * NB;
                    #pragma unroll
                    for (int i = 0; i < 11; ++i) {
                        const float2 pe = rot[i];
                        rot[i] = gp[(size_t)i * NB];     // load t+11
                        d2[i * 64] = prod_step(pe);
                    }
                } else {                                 // final-batch drain
                    #pragma unroll
                    for (int i = 0; i < 11; ++i)
                        d2[i * 64] = prod_step(rot[i]);
                }
            }
            __hip_atomic_store(&produced, k + 1, __ATOMIC_RELEASE,
                               __HIP_MEMORY_SCOPE_WORKGROUP);
        }
    } else {
        // ============ consumer: conv + r-chain + stores ============
        // Unit-hydrograph ordinates (once; precise powf fine here).
        float u10, u11, u12, u20, u21, u22, u23, u24, u25;
        {
            float sh[3];
            #pragma unroll
            for (int j = 1; j <= 3; ++j)
                sh[j - 1] = powf(fminf((float)j / x4, 1.0f), 2.5f);
            u10 = sh[0]; u11 = sh[1] - sh[0]; u12 = sh[2] - sh[1];
            float s2h[6];
            #pragma unroll
            for (int j = 1; j <= 6; ++j) {
                float rr = (float)j / x4;
                s2h[j - 1] = ((float)j <= x4) ? 0.5f * powf(rr, 2.5f)
                           : 1.0f - 0.5f * powf(fmaxf(2.0f - rr, 0.0f), 2.5f);
            }
            u20 = s2h[0];          u21 = s2h[1] - s2h[0]; u22 = s2h[2] - s2h[1];
            u23 = s2h[3] - s2h[2]; u24 = s2h[4] - s2h[3]; u25 = s2h[5] - s2h[4];
        }

        float r = 0.5f * x3;
        float ph0 = 0.f, ph1 = 0.f, ph2 = 0.f, ph3 = 0.f, ph4 = 0.f;

        auto w1_step = [&](float pr) -> float {
            const float q9 = fmaf(u10, pr, fmaf(u11, ph0, u12 * ph1));
            const float q1 = fmaf(u20, pr, fmaf(u21, ph0, fmaf(u22, ph1,
                             fmaf(u23, ph2, fmaf(u24, ph3, u25 * ph4)))));
            ph4 = ph3; ph3 = ph2; ph2 = ph1; ph1 = ph0; ph0 = pr;
            const float rq = r + q9;                 // off the gex path
            const float rx = r * invx3;
            const float srx = __builtin_amdgcn_sqrtf(rx);
            const float gex = (x2 * ((rx * rx) * rx)) * srx; // x2*(r/x3)^3.5
            const float r2 = fmaxf(0.0f, rq + gex);
            const float r22 = r2 * r2;
            const float r24 = r22 * r22;
            const float v4p1 = fmaf(c4r, r24, 1.0f);
            const float rn = r2 * __builtin_amdgcn_rsqf(__builtin_amdgcn_sqrtf(v4p1));
            const float qr = r2 - rn;
            r = rn;
            return qr + fmaxf(0.0f, q1 + gex);
        };

        for (int k = 0; k < NBATCH; ++k) {
            while (__hip_atomic_load(&produced, __ATOMIC_ACQUIRE,
                                     __HIP_MEMORY_SCOPE_WORKGROUP) < k + 1) {}
            const float* src = &prbuf[k & 1][0] + lane;
            if (k != 6) {
                // k<6: t=55k..55k+54 <= 329 -> dump rows [t] (overwritten by
                // t'=365+row later, same wave => ordered). k>=7: rows t-365.
                float* ob = (k < 6)
                    ? out + (size_t)(k * BSTEP) * NB + b
                    : out + (size_t)(k * BSTEP - NWARM) * NB + b;
                float prr[11];
                #pragma unroll
                for (int i = 0; i < 11; ++i) prr[i] = src[i * 64];
                for (int g = 0; g < 5; ++g) {
                    const float* sp = src + (g + 1) * (11 * 64);
                    float* ob2 = ob + (size_t)(g * 11) * NB;
                    if (g < 4) {
                        #pragma unroll
                        for (int i = 0; i < 11; ++i) {
                            const float pr = prr[i];
                            prr[i] = sp[i * 64];         // prefetch 11 ahead
                            ob2[(size_t)i * NB] = w1_step(pr);
                        }
                    } else {
                        #pragma unroll
                        for (int i = 0; i < 11; ++i)
                            ob2[(size_t)i * NB] = w1_step(prr[i]);
                    }
                }
            } else {
                // Special batch k=6: t=330..384. Conv-history reset before
                // t=365 (j==35); store base switches dump->real. Fully
                // unrolled so all conditions fold at compile time.
                float* dumpb = out + (size_t)330 * NB + b;   // rows 330..364
                float* realb = out + b;                      // rows 0..19
                float prr[11];
                #pragma unroll
                for (int i = 0; i < 11; ++i) prr[i] = src[i * 64];
                #pragma unroll
                for (int g = 0; g < 5; ++g) {
                    #pragma unroll
                    for (int i = 0; i < 11; ++i) {
                        const int j = g * 11 + i;            // step in batch
                        const float pr = prr[i];
                        if (g < 4) prr[i] = src[(j + 11) * 64];
                        if (j == 35) { ph0 = ph1 = ph2 = ph3 = ph4 = 0.0f; }
                        const float q = w1_step(pr);
                        if (j < 35) dumpb[(size_t)j * NB] = q;
                        else        realb[(size_t)(j - 35) * NB] = q;
                    }
                }
            }
            __hip_atomic_store(&consumed, k + 1, __ATOMIC_RELEASE,
                               __HIP_MEMORY_SCOPE_WORKGROUP);
        }
    }
}

extern "C" void kernel_launch(void* const* d_in, const int* in_sizes, int n_in,
                              void* d_out, int out_size, void* d_ws, size_t ws_size,
                              hipStream_t stream) {
    const float2* pe_in  = (const float2*)d_in[0];   // p_and_e [4015,2048,2]
    const float*  params = (const float*)d_in[1];    // parameters [2048,4]
    float* out = (float*)d_out;                      // [3650,2048,1]
    (void)in_sizes; (void)n_in; (void)out_size; (void)d_ws; (void)ws_size;

    gr4j_kernel<<<dim3(NB / 64), dim3(128), 0, stream>>>(pe_in, params, out);
}